// Round 6
// baseline (454.999 us; speedup 1.0000x reference)
//
#include <hip/hip_runtime.h>
#include <hip/hip_bf16.h>
#include <hip/hip_cooperative_groups.h>

namespace cg = cooperative_groups;

#define B_ 4
#define T_ 256
#define S_ 256
#define D_ 512
#define TB 2   // t's per attention block

typedef __bf16 bf16x8 __attribute__((ext_vector_type(8)));
typedef float  floatx4 __attribute__((ext_vector_type(4)));
typedef float  floatx2 __attribute__((ext_vector_type(2)));

#define C2F 2.885390081777926f  // 2*log2(e)

static __device__ __forceinline__ unsigned short f2bf(float x) {
    __hip_bfloat16 h = __float2bfloat16(x);
    return *reinterpret_cast<unsigned short*>(&h);
}
static __device__ __forceinline__ float asf(unsigned int u) {
    float f; __builtin_memcpy(&f, &u, 4); return f;
}
static __device__ __forceinline__ float clamp_pos(float x) {
    return fminf(fmaxf(x, 1e-15f), 1e15f);
}

// ===========================================================================
// MEGA: one cooperative dispatch = prep -> 4 GEMMs -> fused attention.
// 512 blocks x 512 threads = exactly 2 blocks/CU co-resident (LDS 28.2 KB,
// VGPR capped 128 via launch_bounds(512,4)). grid.sync() between phases.
// Eliminates 2 inter-kernel launch gaps + 2 ramp-down tails.
// ===========================================================================
__global__ __launch_bounds__(512, 4) void mega(
    const float* __restrict__ output, const float* __restrict__ context,
    const int* __restrict__ mask,
    const float* __restrict__ Wq, const float* __restrict__ bq,
    const float* __restrict__ Wc, const float* __restrict__ v,
    const float* __restrict__ Wout, const float* __restrict__ bout,
    unsigned short* __restrict__ out_f, unsigned short* __restrict__ ctx_f,
    unsigned short* __restrict__ Wq_f, unsigned short* __restrict__ Wc_f,
    unsigned short* __restrict__ WoT_f, unsigned short* __restrict__ WoB_f,
    float* __restrict__ Hb, unsigned short* __restrict__ Wb,
    unsigned short* __restrict__ CWb, float* __restrict__ OB,
    float* __restrict__ attn_out, float* __restrict__ out)
{
    cg::grid_group grid = cg::this_grid();
    const int tid = threadIdx.x;
    const int bx  = blockIdx.x;

    __shared__ union ShU {
        float wtile[2][32][33];          // phase P: 8.4 KB
        struct {
            float  w_s[TB][D_];          // 4 KB
            float  v_s[D_];              // 2 KB
            float2 part[2][256];         // 4 KB
            float2 wred[4];
            float  a_s[TB][256];         // 2 KB
            float  mixp[4][TB][D_];      // 16 KB
        } A;                             // 28.1 KB
    } sh;

    // ---------------- Phase P: fragment-order bf16 conversion --------------
    // Fragment layout (K=512 => 16 k-blocks of 32):
    //   tile(mblk,kblk) = mblk*16 + kblk;  lane = (m&15) | (((k>>3)&3)<<4)
    //   addr = (tile*64 + lane)*8 + (k&7)
    {
        // activations: 2048 frag tiles, 8 per block for blocks 0..255
        const int gt = bx * 8 + (tid >> 6);
        if (gt < 2048) {
            const float* src = (gt < 1024) ? output : context;
            unsigned short* dst = (gt < 1024) ? out_f : ctx_f;
            const int tile = gt & 1023;
            const int lane = tid & 63;
            const int mblk = tile >> 4, kblk = tile & 15;
            const float* s = src + (size_t)(mblk * 16 + (lane & 15)) * 512
                                 + kblk * 32 + (lane >> 4) * 8;
            float4 a = *(const float4*)s;
            float4 b2 = *(const float4*)(s + 4);
            uint4 pk;
            pk.x = (unsigned)f2bf(a.x)  | ((unsigned)f2bf(a.y)  << 16);
            pk.y = (unsigned)f2bf(a.z)  | ((unsigned)f2bf(a.w)  << 16);
            pk.z = (unsigned)f2bf(b2.x) | ((unsigned)f2bf(b2.y) << 16);
            pk.w = (unsigned)f2bf(b2.z) | ((unsigned)f2bf(b2.w) << 16);
            *(uint4*)(dst + (size_t)tile * 512 + lane * 8) = pk;
        }
    }
    {
        // weights: 1024 transpose tiles (4 weights x 256), 2 per block
        const int job  = bx * 2 + (tid >> 8);   // 0..1023
        const int wsel = job >> 8, ti = job & 255;
        const float* W; unsigned short* WF; int krow0;
        if      (wsel == 0) { W = Wq;   WF = Wq_f;  krow0 = 0;   }
        else if (wsel == 1) { W = Wc;   WF = Wc_f;  krow0 = 0;   }
        else if (wsel == 2) { W = Wout; WF = WoT_f; krow0 = 0;   }
        else                { W = Wout; WF = WoB_f; krow0 = 512; }
        const int n0 = (ti & 15) * 32;
        const int k0 = (ti >> 4) * 32;
        float (*tile)[33] = sh.wtile[tid >> 8];
        const int t = tid & 255, c = t & 31, r = t >> 5;
        #pragma unroll
        for (int i = 0; i < 4; ++i)
            tile[r + 8 * i][c] = W[(size_t)(krow0 + k0 + r + 8 * i) * 512 + n0 + c];
        __syncthreads();
        #pragma unroll
        for (int i = 0; i < 4; ++i) {
            const int n = n0 + r + 8 * i;
            const int k = k0 + c;
            const int tl = (n >> 4) * 16 + (k >> 5);
            const int ln = (n & 15) | (((k >> 3) & 3) << 4);
            WF[((size_t)tl * 64 + ln) * 8 + (k & 7)] = f2bf(tile[c][r + 8 * i]);
        }
    }
    __threadfence();
    grid.sync();

    // ---------------- Phase G: four GEMMs (M=1024,N=512,K=512) -------------
    // 8 waves/block, wave tile 16m x 32n (1 A + 2 B loads -> 2 MFMAs per kb).
    // Epilogue modes:
    //   1: H = clamp(exp2(C2F*(acc+bq[col])))      fp32 (B,T,D)
    //   3: W = clamp(exp2(C2F*acc)*rcp(v), +-1e20) bf16 [b][d>>3][s][8]
    //   4: fp32 acc + bout[col]                    (OB)
    //   5: bf16 acc, natural [row][col]            (CWb)
    {
        const int bz = bx >> 7;            // 0..3 (gemm id)
        const int bm = (bx >> 2) & 31;     // 0..31
        const int bn = bx & 3;             // 0..3
        const unsigned short *Af, *Bf; const float* aux; void* Cp; int mode;
        if      (bz == 0) { Af = out_f; Bf = Wq_f;  aux = bq;      Cp = Hb;  mode = 1; }
        else if (bz == 1) { Af = ctx_f; Bf = Wc_f;  aux = v;       Cp = Wb;  mode = 3; }
        else if (bz == 2) { Af = out_f; Bf = WoB_f; aux = bout;    Cp = OB;  mode = 4; }
        else              { Af = ctx_f; Bf = WoT_f; aux = nullptr; Cp = CWb; mode = 5; }

        const int wave = tid >> 6, lane = tid & 63;
        const int l15 = lane & 15, quad = lane >> 4;
        const int wm = wave >> 2, wn = wave & 3;
        const int mblk = bm * 2 + wm;          // 0..63
        const int nb0  = (bn * 4 + wn) * 2;    // 0..30

        const unsigned short* Ap  = Af + ((size_t)mblk * 16 * 64 + lane) * 8;
        const unsigned short* Bp0 = Bf + ((size_t)nb0 * 16 * 64 + lane) * 8;
        const unsigned short* Bp1 = Bp0 + (size_t)16 * 64 * 8;

        floatx4 acc[2];
        acc[0] = (floatx4){0.f, 0.f, 0.f, 0.f};
        acc[1] = (floatx4){0.f, 0.f, 0.f, 0.f};

        #pragma unroll 4
        for (int k = 0; k < 16; ++k) {
            bf16x8 a  = *(const bf16x8*)(Ap  + k * 512);
            bf16x8 b0 = *(const bf16x8*)(Bp0 + k * 512);
            bf16x8 b1 = *(const bf16x8*)(Bp1 + k * 512);
            acc[0] = __builtin_amdgcn_mfma_f32_16x16x32_bf16(a, b0, acc[0], 0, 0, 0);
            acc[1] = __builtin_amdgcn_mfma_f32_16x16x32_bf16(a, b1, acc[1], 0, 0, 0);
        }

        #pragma unroll
        for (int ni = 0; ni < 2; ++ni) {
            const int col = (nb0 + ni) * 16 + l15;
            const int rbase = mblk * 16 + quad * 4;
            if (mode == 1) {
                float* Cf = (float*)Cp;
                float bv = aux[col];
                #pragma unroll
                for (int r = 0; r < 4; ++r) {
                    float hh = __builtin_amdgcn_exp2f(C2F * (acc[ni][r] + bv));
                    Cf[(size_t)(rbase + r) * 512 + col] = clamp_pos(hh);
                }
            } else if (mode == 3) {
                unsigned short* Cb = (unsigned short*)Cp;
                float rv = __builtin_amdgcn_rcpf(aux[col]);
                rv = fminf(fmaxf(rv, -1e30f), 1e30f);
                #pragma unroll
                for (int r = 0; r < 4; ++r) {
                    int row = rbase + r, bb = row >> 8, ss = row & 255;
                    float ww = __builtin_amdgcn_exp2f(C2F * acc[ni][r]) * rv;
                    ww = fminf(fmaxf(ww, -1e20f), 1e20f);
                    Cb[((size_t)(bb * 64 + (col >> 3)) * 256 + ss) * 8 + (col & 7)]
                        = f2bf(ww);
                }
            } else if (mode == 5) {
                unsigned short* Cb = (unsigned short*)Cp;
                #pragma unroll
                for (int r = 0; r < 4; ++r)
                    Cb[(size_t)(rbase + r) * 512 + col] = f2bf(acc[ni][r]);
            } else {   // mode 4
                float* Cf = (float*)Cp;
                float bv = aux[col];
                #pragma unroll
                for (int r = 0; r < 4; ++r)
                    Cf[(size_t)(rbase + r) * 512 + col] = acc[ni][r] + bv;
            }
        }
    }
    __threadfence();
    grid.sync();

    // ---------------- Phase A: score + masked softmax + out-projection -----
    // v*sigmoid(-2(w+u)) = 1/(1/v + H*W); pair combine with ONE rcp:
    //   1/x0 + 1/x1 = (x0+x1)*rcp(x0*x1)   (x single-signed: no cancellation)
    {
        const int bg = (bx & 7) * (B_ * T_ / TB / 8) + (bx >> 3);  // XCD swizzle
        const int b   = bg / (T_ / TB);
        const int t0  = (bg % (T_ / TB)) * TB;
        const int s   = tid & 255;
        const int h   = tid >> 8;    // 0..1 (d-half)

        sh.A.w_s[0][tid] = Hb[(size_t)(b * T_ + t0 + 0) * D_ + tid];
        sh.A.w_s[1][tid] = Hb[(size_t)(b * T_ + t0 + 1) * D_ + tid];
        {
            float iv = __builtin_amdgcn_rcpf(v[tid]);
            sh.A.v_s[tid] = fminf(fmaxf(iv, -1e30f), 1e30f);
        }
        __syncthreads();

        float acc0 = 0.f, acc1 = 0.f;
        const uint4* wb4 = (const uint4*)(Wb + ((size_t)(b * 64 + h * 32) * 256 + s) * 8);

        #pragma unroll 4
        for (int dd = 0; dd < 32; ++dd) {
            uint4 ww = wb4[(size_t)dd * 256];
            floatx2 W01 = {asf(ww.x << 16), asf(ww.x & 0xffff0000u)};
            floatx2 W23 = {asf(ww.y << 16), asf(ww.y & 0xffff0000u)};
            floatx2 W45 = {asf(ww.z << 16), asf(ww.z & 0xffff0000u)};
            floatx2 W67 = {asf(ww.w << 16), asf(ww.w & 0xffff0000u)};

            const int dbase = (h * 32 + dd) * 8;
            float4 iva = *(const float4*)&sh.A.v_s[dbase];
            float4 ivb = *(const float4*)&sh.A.v_s[dbase + 4];
            float4 h0a = *(const float4*)&sh.A.w_s[0][dbase];
            float4 h0b = *(const float4*)&sh.A.w_s[0][dbase + 4];
            float4 h1a = *(const float4*)&sh.A.w_s[1][dbase];
            float4 h1b = *(const float4*)&sh.A.w_s[1][dbase + 4];

            #define PAIR(Wp, Hx, Hy, Ix, Iy, A_)                                \
            {                                                                   \
                floatx2 hh = {Hx, Hy};                                          \
                floatx2 ii = {Ix, Iy};                                          \
                floatx2 x = __builtin_elementwise_fma(hh, Wp, ii);              \
                A_ = fmaf(x.x + x.y, __builtin_amdgcn_rcpf(x.x * x.y), A_);     \
            }
            PAIR(W01, h0a.x, h0a.y, iva.x, iva.y, acc0)
            PAIR(W01, h1a.x, h1a.y, iva.x, iva.y, acc1)
            PAIR(W23, h0a.z, h0a.w, iva.z, iva.w, acc0)
            PAIR(W23, h1a.z, h1a.w, iva.z, iva.w, acc1)
            PAIR(W45, h0b.x, h0b.y, ivb.x, ivb.y, acc0)
            PAIR(W45, h1b.x, h1b.y, ivb.x, ivb.y, acc1)
            PAIR(W67, h0b.z, h0b.w, ivb.z, ivb.w, acc0)
            PAIR(W67, h1b.z, h1b.w, ivb.z, ivb.w, acc1)
            #undef PAIR
        }
        sh.A.part[h][s] = make_float2(acc0, acc1);
        __syncthreads();

        float p0 = 0.f, p1 = 0.f;
        if (tid < 256) {
            float A0 = sh.A.part[0][tid].x + sh.A.part[1][tid].x;
            float A1 = sh.A.part[0][tid].y + sh.A.part[1][tid].y;
            float keep = 1.0f - (float)mask[b * S_ + tid];
            p0 = __builtin_amdgcn_exp2f(-C2F * A0) * keep;
            p1 = __builtin_amdgcn_exp2f(-C2F * A1) * keep;
            float s0 = p0, s1 = p1;
            #pragma unroll
            for (int off = 1; off < 64; off <<= 1) {
                s0 += __shfl_xor(s0, off);
                s1 += __shfl_xor(s1, off);
            }
            if ((tid & 63) == 0) sh.A.wred[tid >> 6] = make_float2(s0, s1);
        }
        __syncthreads();

        if (tid < 256) {
            float den0 = sh.A.wred[0].x + sh.A.wred[1].x + sh.A.wred[2].x + sh.A.wred[3].x;
            float den1 = sh.A.wred[0].y + sh.A.wred[1].y + sh.A.wred[2].y + sh.A.wred[3].y;
            float a0 = p0 * __builtin_amdgcn_rcpf(den0);
            float a1 = p1 * __builtin_amdgcn_rcpf(den1);
            attn_out[(size_t)(b * T_ + t0 + 0) * S_ + tid] = a0;
            attn_out[(size_t)(b * T_ + t0 + 1) * S_ + tid] = a1;
            sh.A.a_s[0][tid] = a0;
            sh.A.a_s[1][tid] = a1;
        }
        __syncthreads();

        // out-projection: thread (dq -> d=4dq..4dq+3), s-quarter sq
        const int dq = tid & 127, sq = tid >> 7;
        const int shh = sq * 64;
        const unsigned short* cw = CWb + ((size_t)(b * S_) + shh) * D_ + 4 * dq;
        float m[TB][4] = {};
        #pragma unroll 8
        for (int s2 = 0; s2 < 64; ++s2) {
            uint2 cc = *(const uint2*)(cw + (size_t)s2 * D_);
            float c0 = asf(cc.x << 16), c1 = asf(cc.x & 0xffff0000u);
            float c2 = asf(cc.y << 16), c3 = asf(cc.y & 0xffff0000u);
            #pragma unroll
            for (int t = 0; t < TB; ++t) {
                float a = sh.A.a_s[t][shh + s2];
                m[t][0] = fmaf(a, c0, m[t][0]);
                m[t][1] = fmaf(a, c1, m[t][1]);
                m[t][2] = fmaf(a, c2, m[t][2]);
                m[t][3] = fmaf(a, c3, m[t][3]);
            }
        }
        #pragma unroll
        for (int t = 0; t < TB; ++t)
            *(float4*)&sh.A.mixp[sq][t][4 * dq]
                = make_float4(m[t][0], m[t][1], m[t][2], m[t][3]);
        __syncthreads();

        #pragma unroll
        for (int t = 0; t < TB; ++t) {
            const int d = tid;
            size_t idx = (size_t)(b * T_ + t0 + t) * D_ + d;
            out[idx] = sh.A.mixp[0][t][d] + sh.A.mixp[1][t][d]
                     + sh.A.mixp[2][t][d] + sh.A.mixp[3][t][d] + OB[idx];
        }
    }
}

// ===========================================================================
// Fallback path (3 dispatches) — used only if cooperative launch fails.
// ===========================================================================

__global__ __launch_bounds__(256) void prep(
    const float* __restrict__ output, const float* __restrict__ context,
    const float* __restrict__ Wq, const float* __restrict__ Wc,
    const float* __restrict__ Wout,
    unsigned short* __restrict__ out_f, unsigned short* __restrict__ ctx_f,
    unsigned short* __restrict__ Wq_f, unsigned short* __restrict__ Wc_f,
    unsigned short* __restrict__ WoT_f, unsigned short* __restrict__ WoB_f)
{
    const int tid = threadIdx.x;
    const int z = blockIdx.z;

    if (z >= 4) {
        const float* src = (z == 4) ? output : context;
        unsigned short* dst = (z == 4) ? out_f : ctx_f;
        const int bid  = blockIdx.y * 16 + blockIdx.x;
        const int tile = bid * 4 + (tid >> 6);
        const int lane = tid & 63;
        const int mblk = tile >> 4, kblk = tile & 15;
        const float* s = src + (size_t)(mblk * 16 + (lane & 15)) * 512
                             + kblk * 32 + (lane >> 4) * 8;
        float4 a = *(const float4*)s;
        float4 b = *(const float4*)(s + 4);
        uint4 pk;
        pk.x = (unsigned)f2bf(a.x) | ((unsigned)f2bf(a.y) << 16);
        pk.y = (unsigned)f2bf(a.z) | ((unsigned)f2bf(a.w) << 16);
        pk.z = (unsigned)f2bf(b.x) | ((unsigned)f2bf(b.y) << 16);
        pk.w = (unsigned)f2bf(b.z) | ((unsigned)f2bf(b.w) << 16);
        *(uint4*)(dst + (size_t)tile * 512 + lane * 8) = pk;
        return;
    }

    const float* W; unsigned short* WF; int krow0;
    if      (z == 0) { W = Wq;   WF = Wq_f;  krow0 = 0;   }
    else if (z == 1) { W = Wc;   WF = Wc_f;  krow0 = 0;   }
    else if (z == 2) { W = Wout; WF = WoT_f; krow0 = 0;   }
    else             { W = Wout; WF = WoB_f; krow0 = 512; }

    const int n0 = blockIdx.x * 32;
    const int k0 = blockIdx.y * 32;

    __shared__ float tile[32][33];
    const int c = tid & 31, r = tid >> 5;
    #pragma unroll
    for (int i = 0; i < 4; ++i)
        tile[r + 8 * i][c] = W[(size_t)(krow0 + k0 + r + 8 * i) * 512 + n0 + c];
    __syncthreads();
    #pragma unroll
    for (int i = 0; i < 4; ++i) {
        const int n = n0 + r + 8 * i;
        const int k = k0 + c;
        const int tl = (n >> 4) * 16 + (k >> 5);
        const int ln = (n & 15) | (((k >> 3) & 3) << 4);
        WF[((size_t)tl * 64 + ln) * 8 + (k & 7)] = f2bf(tile[c][r + 8 * i]);
    }
}

struct GArgs {
    const unsigned short* Af;
    const unsigned short* Bf;
    const float* aux;
    void* C;
    int mode;
};

__global__ __launch_bounds__(256) void gemm2(GArgs g0, GArgs g1, GArgs g2, GArgs g3)
{
    const int z = blockIdx.z;
    GArgs g = (z == 0) ? g0 : (z == 1) ? g1 : (z == 2) ? g2 : g3;

    const int tid  = threadIdx.x;
    const int wave = tid >> 6, lane = tid & 63;
    const int l15  = lane & 15, quad = lane >> 4;
    const int mblk = blockIdx.y * 4 + wave;
    const int nb0  = blockIdx.x * 2;

    const unsigned short* Ap  = g.Af + ((size_t)mblk * 16 * 64 + lane) * 8;
    const unsigned short* Bp0 = g.Bf + ((size_t)nb0 * 16 * 64 + lane) * 8;
    const unsigned short* Bp1 = Bp0 + (size_t)16 * 64 * 8;

    floatx4 acc[2];
    acc[0] = (floatx4){0.f, 0.f, 0.f, 0.f};
    acc[1] = (floatx4){0.f, 0.f, 0.f, 0.f};

    #pragma unroll 4
    for (int k = 0; k < 16; ++k) {
        bf16x8 a  = *(const bf16x8*)(Ap  + k * 512);
        bf16x8 b0 = *(const bf16x8*)(Bp0 + k * 512);
        bf16x8 b1 = *(const bf16x8*)(Bp1 + k * 512);
        acc[0] = __builtin_amdgcn_mfma_f32_16x16x32_bf16(a, b0, acc[0], 0, 0, 0);
        acc[1] = __builtin_amdgcn_mfma_f32_16x16x32_bf16(a, b1, acc[1], 0, 0, 0);
    }

    #pragma unroll
    for (int ni = 0; ni < 2; ++ni) {
        const int col = (nb0 + ni) * 16 + l15;
        const int rbase = mblk * 16 + quad * 4;
        if (g.mode == 1) {
            float* Cf = (float*)g.C;
            float bv = g.aux[col];
            #pragma unroll
            for (int r = 0; r < 4; ++r) {
                float hh = __builtin_amdgcn_exp2f(C2F * (acc[ni][r] + bv));
                Cf[(size_t)(rbase + r) * 512 + col] = clamp_pos(hh);
            }
        } else if (g.mode == 3) {
            unsigned short* Cb = (unsigned short*)g.C;
            float rv = __builtin_amdgcn_rcpf(g.aux[col]);
            rv = fminf(fmaxf(rv, -1e30f), 1e30f);
            #pragma unroll
            for (int r = 0; r < 4; ++r) {
                int row = rbase + r, bb = row >> 8, ss = row & 255;
                float ww = __builtin_amdgcn_exp2f(C2F * acc[ni][r]) * rv;
                ww = fminf(fmaxf(ww, -1e20f), 1e20f);
                Cb[((size_t)(bb * 64 + (col >> 3)) * 256 + ss) * 8 + (col & 7)]
                    = f2bf(ww);
            }
        } else if (g.mode == 5) {
            unsigned short* Cb = (unsigned short*)g.C;
            #pragma unroll
            for (int r = 0; r < 4; ++r)
                Cb[(size_t)(rbase + r) * 512 + col] = f2bf(acc[ni][r]);
        } else {
            float* Cf = (float*)g.C;
            float bv = g.aux[col];
            #pragma unroll
            for (int r = 0; r < 4; ++r)
                Cf[(size_t)(rbase + r) * 512 + col] = acc[ni][r] + bv;
        }
    }
}

__global__ __launch_bounds__(512, 4) void attn_fused(
    const float* __restrict__ Hb,
    const unsigned short* __restrict__ Wb,
    const unsigned short* __restrict__ CWb,
    const float* __restrict__ OB,
    const int*   __restrict__ mask,
    const float* __restrict__ v,
    float* __restrict__ attn_out,
    float* __restrict__ out)
{
    const int bid = blockIdx.x;
    const int bg  = (bid & 7) * (B_ * T_ / TB / 8) + (bid >> 3);
    const int b   = bg / (T_ / TB);
    const int t0  = (bg % (T_ / TB)) * TB;
    const int tid = threadIdx.x;
    const int s   = tid & 255;
    const int h   = tid >> 8;

    __shared__ float  w_s[TB][D_];
    __shared__ float  v_s[D_];
    __shared__ float2 part[2][256];
    __shared__ float2 wred[4];
    __shared__ float  a_s[TB][256];
    __shared__ float  mixp[4][TB][D_];

    w_s[0][tid] = Hb[(size_t)(b * T_ + t0 + 0) * D_ + tid];
    w_s[1][tid] = Hb[(size_t)(b * T_ + t0 + 1) * D_ + tid];
    {
        float iv = __builtin_amdgcn_rcpf(v[tid]);
        v_s[tid] = fminf(fmaxf(iv, -1e30f), 1e30f);
    }
    __syncthreads();

    float acc0 = 0.f, acc1 = 0.f;
    const uint4* wb4 = (const uint4*)(Wb + ((size_t)(b * 64 + h * 32) * 256 + s) * 8);

    #pragma unroll 4
    for (int dd = 0; dd < 32; ++dd) {
        uint4 ww = wb4[(size_t)dd * 256];
        floatx2 W01 = {asf(ww.x << 16), asf(ww.x & 0xffff0000u)};
        floatx2 W23 = {asf(ww.y << 16), asf(ww.y & 0xffff0000u)};
        floatx2 W45 = {asf(ww.z << 16), asf(ww.z & 0xffff0000u)};
        floatx2 W67 = {asf(ww.w << 16), asf(ww.w & 0xffff0000u)};

        const int dbase = (h * 32 + dd) * 8;
        float4 iva = *(const float4*)&v_s[dbase];
        float4 ivb = *(const float4*)&v_s[dbase + 4];
        float4 h0a = *(const float4*)&w_s[0][dbase];
        float4 h0b = *(const float4*)&w_s[0][dbase + 4];
        float4 h1a = *(const float4*)&w_s[1][dbase];
        float4 h1b = *(const float4*)&w_s[1][dbase + 4];

        #define PAIR(Wp, Hx, Hy, Ix, Iy, A_)                                    \
        {                                                                       \
            floatx2 hh = {Hx, Hy};                                              \
            floatx2 ii = {Ix, Iy};                                              \
            floatx2 x = __builtin_elementwise_fma(hh, Wp, ii);                  \
            A_ = fmaf(x.x + x.y, __builtin_amdgcn_rcpf(x.x * x.y), A_);         \
        }
        PAIR(W01, h0a.x, h0a.y, iva.x, iva.y, acc0)
        PAIR(W01, h1a.x, h1a.y, iva.x, iva.y, acc1)
        PAIR(W23, h0a.z, h0a.w, iva.z, iva.w, acc0)
        PAIR(W23, h1a.z, h1a.w, iva.z, iva.w, acc1)
        PAIR(W45, h0b.x, h0b.y, ivb.x, ivb.y, acc0)
        PAIR(W45, h1b.x, h1b.y, ivb.x, ivb.y, acc1)
        PAIR(W67, h0b.z, h0b.w, ivb.z, ivb.w, acc0)
        PAIR(W67, h1b.z, h1b.w, ivb.z, ivb.w, acc1)
        #undef PAIR
    }
    part[h][s] = make_float2(acc0, acc1);
    __syncthreads();

    float p0 = 0.f, p1 = 0.f;
    if (tid < 256) {
        float A0 = part[0][tid].x + part[1][tid].x;
        float A1 = part[0][tid].y + part[1][tid].y;
        float keep = 1.0f - (float)mask[b * S_ + tid];
        p0 = __builtin_amdgcn_exp2f(-C2F * A0) * keep;
        p1 = __builtin_amdgcn_exp2f(-C2F * A1) * keep;
        float s0 = p0, s1 = p1;
        #pragma unroll
        for (int off = 1; off < 64; off <<= 1) {
            s0 += __shfl_xor(s0, off);
            s1 += __shfl_xor(s1, off);
        }
        if ((tid & 63) == 0) wred[tid >> 6] = make_float2(s0, s1);
    }
    __syncthreads();

    if (tid < 256) {
        float den0 = wred[0].x + wred[1].x + wred[2].x + wred[3].x;
        float den1 = wred[0].y + wred[1].y + wred[2].y + wred[3].y;
        float a0 = p0 * __builtin_amdgcn_rcpf(den0);
        float a1 = p1 * __builtin_amdgcn_rcpf(den1);
        attn_out[(size_t)(b * T_ + t0 + 0) * S_ + tid] = a0;
        attn_out[(size_t)(b * T_ + t0 + 1) * S_ + tid] = a1;
        a_s[0][tid] = a0;
        a_s[1][tid] = a1;
    }
    __syncthreads();

    const int dq = tid & 127, sq = tid >> 7;
    const int sh = sq * 64;
    const unsigned short* cw = CWb + ((size_t)(b * S_) + sh) * D_ + 4 * dq;
    float m[TB][4] = {};
    #pragma unroll 8
    for (int s2 = 0; s2 < 64; ++s2) {
        uint2 cc = *(const uint2*)(cw + (size_t)s2 * D_);
        float c0 = asf(cc.x << 16), c1 = asf(cc.x & 0xffff0000u);
        float c2 = asf(cc.y << 16), c3 = asf(cc.y & 0xffff0000u);
        #pragma unroll
        for (int t = 0; t < TB; ++t) {
            float a = a_s[t][sh + s2];
            m[t][0] = fmaf(a, c0, m[t][0]);
            m[t][1] = fmaf(a, c1, m[t][1]);
            m[t][2] = fmaf(a, c2, m[t][2]);
            m[t][3] = fmaf(a, c3, m[t][3]);
        }
    }
    #pragma unroll
    for (int t = 0; t < TB; ++t)
        *(float4*)&mixp[sq][t][4 * dq] = make_float4(m[t][0], m[t][1], m[t][2], m[t][3]);
    __syncthreads();

    #pragma unroll
    for (int t = 0; t < TB; ++t) {
        const int d = tid;
        size_t idx = (size_t)(b * T_ + t0 + t) * D_ + d;
        out[idx] = mixp[0][t][d] + mixp[1][t][d] + mixp[2][t][d] + mixp[3][t][d]
                 + OB[idx];
    }
}

extern "C" void kernel_launch(void* const* d_in, const int* in_sizes, int n_in,
                              void* d_out, int out_size, void* d_ws, size_t ws_size,
                              hipStream_t stream) {
    const float* output  = (const float*)d_in[0];
    const float* context = (const float*)d_in[1];
    const int*   mask    = (const int*)d_in[2];
    const float* Wq      = (const float*)d_in[3];
    const float* bq      = (const float*)d_in[4];
    const float* Wc      = (const float*)d_in[5];
    const float* v       = (const float*)d_in[6];
    const float* Wout    = (const float*)d_in[7];
    const float* bout    = (const float*)d_in[8];

    float* out  = (float*)d_out;                       // (B,T,D)
    float* attn = out + (size_t)B_ * T_ * D_;          // (B,T,S)

    char* ws = (char*)d_ws;
    float* Hb             = (float*)ws;                             // 2 MB
    float* OB             = (float*)(ws + (2u << 20));              // 2 MB
    unsigned short* Wb    = (unsigned short*)(ws + (4u << 20));     // 1 MB
    unsigned short* out_f = (unsigned short*)(ws + (6u << 20));     // 1 MB
    unsigned short* ctx_f = (unsigned short*)(ws + (7u << 20));     // 1 MB
    unsigned short* Wq_f  = (unsigned short*)(ws + (8u << 20));     // 0.5 MB
    unsigned short* Wc_f  = (unsigned short*)(ws + (8u << 20) + (512u << 10));
    unsigned short* WoT_f = (unsigned short*)(ws + (9u << 20));     // 0.5 MB
    unsigned short* WoB_f = (unsigned short*)(ws + (9u << 20) + (512u << 10));
    unsigned short* CWb   = (unsigned short*)(ws + (10u << 20));    // 1 MB

    void* kp[] = {
        (void*)&output, (void*)&context, (void*)&mask,
        (void*)&Wq, (void*)&bq, (void*)&Wc, (void*)&v, (void*)&Wout, (void*)&bout,
        (void*)&out_f, (void*)&ctx_f, (void*)&Wq_f, (void*)&Wc_f,
        (void*)&WoT_f, (void*)&WoB_f,
        (void*)&Hb, (void*)&Wb, (void*)&CWb, (void*)&OB,
        (void*)&attn, (void*)&out
    };
    hipError_t e = hipLaunchCooperativeKernel((const void*)mega, dim3(512), dim3(512),
                                              kp, 0, stream);
    if (e != hipSuccess) {
        // fallback: 3-dispatch path
        dim3 blk(256);
        prep<<<dim3(16, 16, 6), blk, 0, stream>>>(
            output, context, Wq, Wc, Wout, out_f, ctx_f, Wq_f, Wc_f, WoT_f, WoB_f);
        GArgs gwq = { out_f, Wq_f,  bq,   Hb,  1 };
        GArgs guh = { ctx_f, Wc_f,  v,    Wb,  3 };
        GArgs gob = { out_f, WoB_f, bout, OB,  4 };
        GArgs gcw = { ctx_f, WoT_f, NULL, CWb, 5 };
        gemm2<<<dim3(16, 16, 4), blk, 0, stream>>>(gwq, guh, gob, gcw);
        attn_fused<<<dim3(B_ * T_ / TB), dim3(512), 0, stream>>>(
            Hb, Wb, CWb, OB, mask, v, attn, out);
    }
}

// Round 7
// 108.689 us; speedup vs baseline: 4.1863x; 4.1863x over previous
//
#include <hip/hip_runtime.h>
#include <hip/hip_bf16.h>

#define B_ 4
#define T_ 256
#define S_ 256
#define D_ 512
#define TB 2   // t's per attention block

typedef __bf16 bf16x8 __attribute__((ext_vector_type(8)));
typedef float  floatx4 __attribute__((ext_vector_type(4)));
typedef float  floatx2 __attribute__((ext_vector_type(2)));

#define C2F 2.885390081777926f  // 2*log2(e)

static __device__ __forceinline__ unsigned short f2bf(float x) {
    __hip_bfloat16 h = __float2bfloat16(x);
    return *reinterpret_cast<unsigned short*>(&h);
}
static __device__ __forceinline__ float asf(unsigned int u) {
    float f; __builtin_memcpy(&f, &u, 4); return f;
}
static __device__ __forceinline__ float clamp_pos(float x) {
    return fminf(fmaxf(x, 1e-15f), 1e15f);
}

// ---------------------------------------------------------------------------
// Fragment-order layout (K=512 => 16 k-blocks of 32):
//   tile(mblk,kblk) = mblk*16 + kblk;  lane = (m&15) | (((k>>3)&3)<<4)
//   addr = (tile*64 + lane)*8 + (k&7)
// ---------------------------------------------------------------------------

__global__ __launch_bounds__(256) void prep(
    const float* __restrict__ output, const float* __restrict__ context,
    const float* __restrict__ Wq, const float* __restrict__ Wc,
    const float* __restrict__ Wout,
    unsigned short* __restrict__ out_f, unsigned short* __restrict__ ctx_f,
    unsigned short* __restrict__ Wq_f, unsigned short* __restrict__ Wc_f,
    unsigned short* __restrict__ WoT_f, unsigned short* __restrict__ WoB_f)
{
    const int tid = threadIdx.x;
    const int z = blockIdx.z;

    if (z >= 4) {
        const float* src = (z == 4) ? output : context;
        unsigned short* dst = (z == 4) ? out_f : ctx_f;
        const int bid  = blockIdx.y * 16 + blockIdx.x;   // 0..255
        const int tile = bid * 4 + (tid >> 6);           // 0..1023
        const int lane = tid & 63;
        const int mblk = tile >> 4, kblk = tile & 15;
        const float* s = src + (size_t)(mblk * 16 + (lane & 15)) * 512
                             + kblk * 32 + (lane >> 4) * 8;
        float4 a = *(const float4*)s;
        float4 b = *(const float4*)(s + 4);
        uint4 pk;
        pk.x = (unsigned)f2bf(a.x) | ((unsigned)f2bf(a.y) << 16);
        pk.y = (unsigned)f2bf(a.z) | ((unsigned)f2bf(a.w) << 16);
        pk.z = (unsigned)f2bf(b.x) | ((unsigned)f2bf(b.y) << 16);
        pk.w = (unsigned)f2bf(b.z) | ((unsigned)f2bf(b.w) << 16);
        *(uint4*)(dst + (size_t)tile * 512 + lane * 8) = pk;
        return;
    }

    const float* W; unsigned short* WF; int krow0;
    if      (z == 0) { W = Wq;   WF = Wq_f;  krow0 = 0;   }
    else if (z == 1) { W = Wc;   WF = Wc_f;  krow0 = 0;   }
    else if (z == 2) { W = Wout; WF = WoT_f; krow0 = 0;   }
    else             { W = Wout; WF = WoB_f; krow0 = 512; }

    const int n0 = blockIdx.x * 32;
    const int k0 = blockIdx.y * 32;

    __shared__ float tile[32][33];
    const int c = tid & 31, r = tid >> 5;
    #pragma unroll
    for (int i = 0; i < 4; ++i)
        tile[r + 8 * i][c] = W[(size_t)(krow0 + k0 + r + 8 * i) * 512 + n0 + c];
    __syncthreads();
    #pragma unroll
    for (int i = 0; i < 4; ++i) {
        const int n = n0 + r + 8 * i;
        const int k = k0 + c;
        const int tl = (n >> 4) * 16 + (k >> 5);
        const int ln = (n & 15) | (((k >> 3) & 3) << 4);
        WF[((size_t)tl * 64 + ln) * 8 + (k & 7)] = f2bf(tile[c][r + 8 * i]);
    }
}

// ---------------------------------------------------------------------------
// MFMA bf16 GEMM from fragment-order inputs. Wave tile 16m x 32n.
// Epilogue modes:
//   1: H = clamp(exp2(C2F*(acc+bq[col])), 1e-15, 1e15)  fp32 (B,T,D)
//   3: W = clamp(exp2(+C2F*acc) * rcp(v[col]), +-1e20)  bf16 [b][d>>3][s][8]
//   4: bf16 acc + bout[col]                 (OBb = output@Wout_bot + bout)
//   5: bf16 acc, natural [row][col]         (CWb = context@Wout_top)
// ---------------------------------------------------------------------------
struct GArgs {
    const unsigned short* Af;
    const unsigned short* Bf;
    const float* aux;    // bias (modes 1,4) or v (mode 3)
    void* C;
    int mode;
};

__global__ __launch_bounds__(256) void gemm2(GArgs g0, GArgs g1, GArgs g2, GArgs g3)
{
    const int z = blockIdx.z;
    GArgs g = (z == 0) ? g0 : (z == 1) ? g1 : (z == 2) ? g2 : g3;

    const int tid  = threadIdx.x;
    const int wave = tid >> 6, lane = tid & 63;
    const int l15  = lane & 15, quad = lane >> 4;
    const int mblk = blockIdx.y * 4 + wave;      // 0..63
    const int nb0  = blockIdx.x * 2;             // 0..30

    const unsigned short* Ap  = g.Af + ((size_t)mblk * 16 * 64 + lane) * 8;
    const unsigned short* Bp0 = g.Bf + ((size_t)nb0 * 16 * 64 + lane) * 8;
    const unsigned short* Bp1 = Bp0 + (size_t)16 * 64 * 8;

    floatx4 acc[2];
    acc[0] = (floatx4){0.f, 0.f, 0.f, 0.f};
    acc[1] = (floatx4){0.f, 0.f, 0.f, 0.f};

    #pragma unroll 4
    for (int k = 0; k < 16; ++k) {
        bf16x8 a  = *(const bf16x8*)(Ap  + k * 512);
        bf16x8 b0 = *(const bf16x8*)(Bp0 + k * 512);
        bf16x8 b1 = *(const bf16x8*)(Bp1 + k * 512);
        acc[0] = __builtin_amdgcn_mfma_f32_16x16x32_bf16(a, b0, acc[0], 0, 0, 0);
        acc[1] = __builtin_amdgcn_mfma_f32_16x16x32_bf16(a, b1, acc[1], 0, 0, 0);
    }

    #pragma unroll
    for (int ni = 0; ni < 2; ++ni) {
        const int col = (nb0 + ni) * 16 + l15;
        const int rbase = mblk * 16 + quad * 4;
        if (g.mode == 1) {
            float* Cf = (float*)g.C;
            float bv = g.aux[col];
            #pragma unroll
            for (int r = 0; r < 4; ++r) {
                float hh = __builtin_amdgcn_exp2f(C2F * (acc[ni][r] + bv));
                Cf[(size_t)(rbase + r) * 512 + col] = clamp_pos(hh);
            }
        } else if (g.mode == 3) {
            unsigned short* Cb = (unsigned short*)g.C;
            float rv = __builtin_amdgcn_rcpf(g.aux[col]);   // 1/v_col
            rv = fminf(fmaxf(rv, -1e30f), 1e30f);
            #pragma unroll
            for (int r = 0; r < 4; ++r) {
                int row = rbase + r, bb = row >> 8, ss = row & 255;
                float ww = __builtin_amdgcn_exp2f(C2F * acc[ni][r]) * rv;
                ww = fminf(fmaxf(ww, -1e20f), 1e20f);
                Cb[((size_t)(bb * 64 + (col >> 3)) * 256 + ss) * 8 + (col & 7)]
                    = f2bf(ww);
            }
        } else if (g.mode == 5) {
            unsigned short* Cb = (unsigned short*)g.C;
            #pragma unroll
            for (int r = 0; r < 4; ++r)
                Cb[(size_t)(rbase + r) * 512 + col] = f2bf(acc[ni][r]);
        } else {   // mode 4: bf16 with bias
            unsigned short* Cb = (unsigned short*)g.C;
            float bv = g.aux[col];
            #pragma unroll
            for (int r = 0; r < 4; ++r)
                Cb[(size_t)(rbase + r) * 512 + col] = f2bf(acc[ni][r] + bv);
        }
    }
}

// ---------------------------------------------------------------------------
// Fused score + masked softmax + out-projection. 512 threads (8 waves).
// Score: v*sigmoid(-2(w+u)) = 1/(1/v + H*W),  H=e^{2w} (t,d), W=e^{2u}/v (s,d).
// x = iv + H*W is single-signed -> no cancellation. Pair combine, ONE rcp:
//   1/x0 + 1/x1 = (x0+x1) * rcp(x0*x1)
// W-stream: explicit 4-deep prefetch pipeline (the stream is cold in L3/HBM
// after the inter-kernel L2 writeback; keeping >=4 dwordx4 loads in flight
// hides the ~600-900 cyc miss latency under the PAIR compute).
// Softmax: p = exp2(-C2F*A) directly (shift-invariance).
// Out-proj: thread owns 4 consecutive d's x one s-quarter -> 8B/lane loads.
// XCD swizzle: chunk so each XCD keeps one b-half's streams in its L2.
// ---------------------------------------------------------------------------
__global__ __launch_bounds__(512, 4) void attn_fused(
    const float* __restrict__ Hb,             // (B,T,D) fp32  e^{2w}
    const unsigned short* __restrict__ Wb,    // (B,D/8,S,8) bf16  e^{2u}/v
    const unsigned short* __restrict__ CWb,   // (B,S,D) bf16
    const unsigned short* __restrict__ OBb,   // (B,T,D) bf16
    const int*   __restrict__ mask,           // (B,S)
    const float* __restrict__ v,              // (D)
    float* __restrict__ attn_out,             // (B,T,S) fp32
    float* __restrict__ out)                  // (B,T,D) fp32
{
    // bijective XCD chunk swizzle (512 % 8 == 0)
    const int bid = blockIdx.x;
    const int bg  = (bid & 7) * (B_ * T_ / TB / 8) + (bid >> 3);
    const int b   = bg / (T_ / TB);
    const int t0  = (bg % (T_ / TB)) * TB;
    const int tid = threadIdx.x;
    const int s   = tid & 255;
    const int h   = tid >> 8;    // 0..1  (d-half in score)

    __shared__ float  w_s[TB][D_];       // 4 KB (H rows)
    __shared__ float  v_s[D_];           // 2 KB (1/v)
    __shared__ float2 part[2][256];      // 4 KB
    __shared__ float2 wred[4];
    __shared__ float  a_s[TB][256];      // 2 KB
    __shared__ float  mixp[4][TB][D_];   // 16 KB

    w_s[0][tid] = Hb[(size_t)(b * T_ + t0 + 0) * D_ + tid];
    w_s[1][tid] = Hb[(size_t)(b * T_ + t0 + 1) * D_ + tid];
    {
        float iv = __builtin_amdgcn_rcpf(v[tid]);
        v_s[tid] = fminf(fmaxf(iv, -1e30f), 1e30f);
    }
    __syncthreads();

    float acc0 = 0.f, acc1 = 0.f;
    const uint4* wb4 = (const uint4*)(Wb + ((size_t)(b * 64 + h * 32) * 256 + s) * 8);

    // 4-deep prefetch pipeline over the 32 W-chunks
    uint4 buf0 = wb4[0 * 256];
    uint4 buf1 = wb4[1 * 256];
    uint4 buf2 = wb4[2 * 256];
    uint4 buf3 = wb4[3 * 256];

    #pragma unroll
    for (int dd0 = 0; dd0 < 32; dd0 += 4) {
        uint4 c0 = buf0, c1 = buf1, c2 = buf2, c3 = buf3;
        if (dd0 + 4 < 32) {
            buf0 = wb4[(size_t)(dd0 + 4) * 256];
            buf1 = wb4[(size_t)(dd0 + 5) * 256];
            buf2 = wb4[(size_t)(dd0 + 6) * 256];
            buf3 = wb4[(size_t)(dd0 + 7) * 256];
        }
        #pragma unroll
        for (int i = 0; i < 4; ++i) {
            const uint4 ww = (i == 0) ? c0 : (i == 1) ? c1 : (i == 2) ? c2 : c3;
            const int dd = dd0 + i;
            floatx2 W01 = {asf(ww.x << 16), asf(ww.x & 0xffff0000u)};
            floatx2 W23 = {asf(ww.y << 16), asf(ww.y & 0xffff0000u)};
            floatx2 W45 = {asf(ww.z << 16), asf(ww.z & 0xffff0000u)};
            floatx2 W67 = {asf(ww.w << 16), asf(ww.w & 0xffff0000u)};

            const int dbase = (h * 32 + dd) * 8;
            float4 iva = *(const float4*)&v_s[dbase];
            float4 ivb = *(const float4*)&v_s[dbase + 4];
            float4 h0a = *(const float4*)&w_s[0][dbase];
            float4 h0b = *(const float4*)&w_s[0][dbase + 4];
            float4 h1a = *(const float4*)&w_s[1][dbase];
            float4 h1b = *(const float4*)&w_s[1][dbase + 4];

            #define PAIR(Wp, Hx, Hy, Ix, Iy, A_)                                \
            {                                                                   \
                floatx2 hh = {Hx, Hy};                                          \
                floatx2 ii = {Ix, Iy};                                          \
                floatx2 x = __builtin_elementwise_fma(hh, Wp, ii);              \
                A_ = fmaf(x.x + x.y, __builtin_amdgcn_rcpf(x.x * x.y), A_);     \
            }
            PAIR(W01, h0a.x, h0a.y, iva.x, iva.y, acc0)
            PAIR(W01, h1a.x, h1a.y, iva.x, iva.y, acc1)
            PAIR(W23, h0a.z, h0a.w, iva.z, iva.w, acc0)
            PAIR(W23, h1a.z, h1a.w, iva.z, iva.w, acc1)
            PAIR(W45, h0b.x, h0b.y, ivb.x, ivb.y, acc0)
            PAIR(W45, h1b.x, h1b.y, ivb.x, ivb.y, acc1)
            PAIR(W67, h0b.z, h0b.w, ivb.z, ivb.w, acc0)
            PAIR(W67, h1b.z, h1b.w, ivb.z, ivb.w, acc1)
            #undef PAIR
        }
    }
    part[h][s] = make_float2(acc0, acc1);
    __syncthreads();

    float p0 = 0.f, p1 = 0.f;
    if (tid < 256) {
        float A0 = part[0][tid].x + part[1][tid].x;
        float A1 = part[0][tid].y + part[1][tid].y;
        float keep = 1.0f - (float)mask[b * S_ + tid];
        p0 = __builtin_amdgcn_exp2f(-C2F * A0) * keep;
        p1 = __builtin_amdgcn_exp2f(-C2F * A1) * keep;
        float s0 = p0, s1 = p1;
        #pragma unroll
        for (int off = 1; off < 64; off <<= 1) {
            s0 += __shfl_xor(s0, off);
            s1 += __shfl_xor(s1, off);
        }
        if ((tid & 63) == 0) wred[tid >> 6] = make_float2(s0, s1);
    }
    __syncthreads();

    if (tid < 256) {
        float den0 = wred[0].x + wred[1].x + wred[2].x + wred[3].x;
        float den1 = wred[0].y + wred[1].y + wred[2].y + wred[3].y;
        float a0 = p0 * __builtin_amdgcn_rcpf(den0);
        float a1 = p1 * __builtin_amdgcn_rcpf(den1);
        attn_out[(size_t)(b * T_ + t0 + 0) * S_ + tid] = a0;
        attn_out[(size_t)(b * T_ + t0 + 1) * S_ + tid] = a1;
        a_s[0][tid] = a0;
        a_s[1][tid] = a1;
    }
    __syncthreads();

    // out-projection: thread (dq=tid&127 -> d=4dq..4dq+3), s-quarter sq=tid>>7
    const int dq = tid & 127, sq = tid >> 7;
    const int sh = sq * 64;
    const unsigned short* cw = CWb + ((size_t)(b * S_) + sh) * D_ + 4 * dq;
    float m[TB][4] = {};
    #pragma unroll 8
    for (int s2 = 0; s2 < 64; ++s2) {
        uint2 cc = *(const uint2*)(cw + (size_t)s2 * D_);   // 8B coalesced
        float c0 = asf(cc.x << 16), c1 = asf(cc.x & 0xffff0000u);
        float c2 = asf(cc.y << 16), c3 = asf(cc.y & 0xffff0000u);
        #pragma unroll
        for (int t = 0; t < TB; ++t) {
            float a = a_s[t][sh + s2];
            m[t][0] = fmaf(a, c0, m[t][0]);
            m[t][1] = fmaf(a, c1, m[t][1]);
            m[t][2] = fmaf(a, c2, m[t][2]);
            m[t][3] = fmaf(a, c3, m[t][3]);
        }
    }
    #pragma unroll
    for (int t = 0; t < TB; ++t)
        *(float4*)&mixp[sq][t][4 * dq] = make_float4(m[t][0], m[t][1], m[t][2], m[t][3]);
    __syncthreads();

    {   // 512 threads cover TB*512 outputs (2 per thread)
        #pragma unroll
        for (int t = 0; t < TB; ++t) {
            const int d = tid;
            size_t idx = (size_t)(b * T_ + t0 + t) * D_ + d;
            float ob = asf((unsigned)OBb[idx] << 16);
            out[idx] = mixp[0][t][d] + mixp[1][t][d] + mixp[2][t][d] + mixp[3][t][d]
                     + ob;
        }
    }
}

extern "C" void kernel_launch(void* const* d_in, const int* in_sizes, int n_in,
                              void* d_out, int out_size, void* d_ws, size_t ws_size,
                              hipStream_t stream) {
    const float* output  = (const float*)d_in[0];
    const float* context = (const float*)d_in[1];
    const int*   mask    = (const int*)d_in[2];
    const float* Wq      = (const float*)d_in[3];
    const float* bq      = (const float*)d_in[4];
    const float* Wc      = (const float*)d_in[5];
    const float* v       = (const float*)d_in[6];
    const float* Wout    = (const float*)d_in[7];
    const float* bout    = (const float*)d_in[8];

    float* out  = (float*)d_out;                       // (B,T,D)
    float* attn = out + (size_t)B_ * T_ * D_;          // (B,T,S)

    char* ws = (char*)d_ws;
    float* Hb             = (float*)ws;                             // 2 MB
    unsigned short* OBb   = (unsigned short*)(ws + (2u << 20));     // 1 MB
    unsigned short* Wb    = (unsigned short*)(ws + (4u << 20));     // 1 MB
    unsigned short* out_f = (unsigned short*)(ws + (6u << 20));     // 1 MB
    unsigned short* ctx_f = (unsigned short*)(ws + (7u << 20));     // 1 MB
    unsigned short* Wq_f  = (unsigned short*)(ws + (8u << 20));     // 0.5 MB
    unsigned short* Wc_f  = (unsigned short*)(ws + (8u << 20) + (512u << 10));
    unsigned short* WoT_f = (unsigned short*)(ws + (9u << 20));     // 0.5 MB
    unsigned short* WoB_f = (unsigned short*)(ws + (9u << 20) + (512u << 10));
    unsigned short* CWb   = (unsigned short*)(ws + (10u << 20));    // 1 MB

    dim3 blk(256);

    prep<<<dim3(16, 16, 6), blk, 0, stream>>>(
        output, context, Wq, Wc, Wout, out_f, ctx_f, Wq_f, Wc_f, WoT_f, WoB_f);

    // four independent GEMMs, one dispatch (z-slices), K=512 each:
    //   z0: Hb  = clamp(exp2(C2*(output@Wq + bq)))        [mode 1]
    //   z1: Wb  = bf16 clamp(exp2(C2*(context@Wc))/v)     [mode 3]
    //   z2: OBb = bf16 (output@Wout_bot + bout)           [mode 4]
    //   z3: CWb = bf16 context@Wout_top                   [mode 5]
    GArgs gwq = { out_f, Wq_f,  bq,   Hb,  1 };
    GArgs guh = { ctx_f, Wc_f,  v,    Wb,  3 };
    GArgs gob = { out_f, WoB_f, bout, OBb, 4 };
    GArgs gcw = { ctx_f, WoT_f, NULL, CWb, 5 };
    gemm2<<<dim3(16, 16, 4), blk, 0, stream>>>(gwq, guh, gob, gcw);

    attn_fused<<<dim3(B_ * T_ / TB), dim3(512), 0, stream>>>(
        Hb, Wb, CWb, OBb, mask, v, attn, out);
}

// Round 8
// 107.672 us; speedup vs baseline: 4.2258x; 1.0094x over previous
//
#include <hip/hip_runtime.h>
#include <hip/hip_bf16.h>

#define B_ 4
#define T_ 256
#define S_ 256
#define D_ 512
#define TB 2   // t's per attention block

typedef __bf16 bf16x8 __attribute__((ext_vector_type(8)));
typedef float  floatx4 __attribute__((ext_vector_type(4)));
typedef float  floatx2 __attribute__((ext_vector_type(2)));

#define C2F 2.885390081777926f  // 2*log2(e)

static __device__ __forceinline__ unsigned short f2bf(float x) {
    __hip_bfloat16 h = __float2bfloat16(x);
    return *reinterpret_cast<unsigned short*>(&h);
}
static __device__ __forceinline__ float asf(unsigned int u) {
    float f; __builtin_memcpy(&f, &u, 4); return f;
}
static __device__ __forceinline__ float clamp_pos(float x) {
    return fminf(fmaxf(x, 1e-15f), 1e15f);
}

// ---------------------------------------------------------------------------
// Fragment-order layout (K=512 => 16 k-blocks of 32):
//   tile(mblk,kblk) = mblk*16 + kblk;  lane = (m&15) | (((k>>3)&3)<<4)
//   addr = (tile*64 + lane)*8 + (k&7)
// ---------------------------------------------------------------------------

__global__ __launch_bounds__(256) void prep(
    const float* __restrict__ output, const float* __restrict__ context,
    const float* __restrict__ Wq, const float* __restrict__ Wc,
    const float* __restrict__ Wout,
    unsigned short* __restrict__ out_f, unsigned short* __restrict__ ctx_f,
    unsigned short* __restrict__ Wq_f, unsigned short* __restrict__ Wc_f,
    unsigned short* __restrict__ WoT_f, unsigned short* __restrict__ WoB_f)
{
    const int tid = threadIdx.x;
    const int z = blockIdx.z;

    if (z >= 4) {
        const float* src = (z == 4) ? output : context;
        unsigned short* dst = (z == 4) ? out_f : ctx_f;
        const int bid  = blockIdx.y * 16 + blockIdx.x;   // 0..255
        const int tile = bid * 4 + (tid >> 6);           // 0..1023
        const int lane = tid & 63;
        const int mblk = tile >> 4, kblk = tile & 15;
        const float* s = src + (size_t)(mblk * 16 + (lane & 15)) * 512
                             + kblk * 32 + (lane >> 4) * 8;
        float4 a = *(const float4*)s;
        float4 b = *(const float4*)(s + 4);
        uint4 pk;
        pk.x = (unsigned)f2bf(a.x) | ((unsigned)f2bf(a.y) << 16);
        pk.y = (unsigned)f2bf(a.z) | ((unsigned)f2bf(a.w) << 16);
        pk.z = (unsigned)f2bf(b.x) | ((unsigned)f2bf(b.y) << 16);
        pk.w = (unsigned)f2bf(b.z) | ((unsigned)f2bf(b.w) << 16);
        *(uint4*)(dst + (size_t)tile * 512 + lane * 8) = pk;
        return;
    }

    const float* W; unsigned short* WF; int krow0;
    if      (z == 0) { W = Wq;   WF = Wq_f;  krow0 = 0;   }
    else if (z == 1) { W = Wc;   WF = Wc_f;  krow0 = 0;   }
    else if (z == 2) { W = Wout; WF = WoT_f; krow0 = 0;   }
    else             { W = Wout; WF = WoB_f; krow0 = 512; }

    const int n0 = blockIdx.x * 32;
    const int k0 = blockIdx.y * 32;

    __shared__ float tile[32][33];
    const int c = tid & 31, r = tid >> 5;
    #pragma unroll
    for (int i = 0; i < 4; ++i)
        tile[r + 8 * i][c] = W[(size_t)(krow0 + k0 + r + 8 * i) * 512 + n0 + c];
    __syncthreads();
    #pragma unroll
    for (int i = 0; i < 4; ++i) {
        const int n = n0 + r + 8 * i;
        const int k = k0 + c;
        const int tl = (n >> 4) * 16 + (k >> 5);
        const int ln = (n & 15) | (((k >> 3) & 3) << 4);
        WF[((size_t)tl * 64 + ln) * 8 + (k & 7)] = f2bf(tile[c][r + 8 * i]);
    }
}

// ---------------------------------------------------------------------------
// MFMA bf16 GEMM from fragment-order inputs. Wave tile 16m x 32n.
// Epilogue modes:
//   1: H = clamp(exp2(C2F*(acc+bq[col])), 1e-15, 1e15)  fp32 (B,T,D)
//   3: W = clamp(exp2(+C2F*acc) * rcp(v[col]), +-1e20)  bf16 [b][d>>3][s][8]
//   4: bf16 acc + bout[col]                 (OBb = output@Wout_bot + bout)
//   5: bf16 acc, natural [row][col]         (CWb = context@Wout_top)
// ---------------------------------------------------------------------------
struct GArgs {
    const unsigned short* Af;
    const unsigned short* Bf;
    const float* aux;    // bias (modes 1,4) or v (mode 3)
    void* C;
    int mode;
};

__global__ __launch_bounds__(256) void gemm2(GArgs g0, GArgs g1, GArgs g2, GArgs g3)
{
    const int z = blockIdx.z;
    GArgs g = (z == 0) ? g0 : (z == 1) ? g1 : (z == 2) ? g2 : g3;

    const int tid  = threadIdx.x;
    const int wave = tid >> 6, lane = tid & 63;
    const int l15  = lane & 15, quad = lane >> 4;
    const int mblk = blockIdx.y * 4 + wave;      // 0..63
    const int nb0  = blockIdx.x * 2;             // 0..30

    const unsigned short* Ap  = g.Af + ((size_t)mblk * 16 * 64 + lane) * 8;
    const unsigned short* Bp0 = g.Bf + ((size_t)nb0 * 16 * 64 + lane) * 8;
    const unsigned short* Bp1 = Bp0 + (size_t)16 * 64 * 8;

    floatx4 acc[2];
    acc[0] = (floatx4){0.f, 0.f, 0.f, 0.f};
    acc[1] = (floatx4){0.f, 0.f, 0.f, 0.f};

    #pragma unroll 4
    for (int k = 0; k < 16; ++k) {
        bf16x8 a  = *(const bf16x8*)(Ap  + k * 512);
        bf16x8 b0 = *(const bf16x8*)(Bp0 + k * 512);
        bf16x8 b1 = *(const bf16x8*)(Bp1 + k * 512);
        acc[0] = __builtin_amdgcn_mfma_f32_16x16x32_bf16(a, b0, acc[0], 0, 0, 0);
        acc[1] = __builtin_amdgcn_mfma_f32_16x16x32_bf16(a, b1, acc[1], 0, 0, 0);
    }

    #pragma unroll
    for (int ni = 0; ni < 2; ++ni) {
        const int col = (nb0 + ni) * 16 + l15;
        const int rbase = mblk * 16 + quad * 4;
        if (g.mode == 1) {
            float* Cf = (float*)g.C;
            float bv = g.aux[col];
            #pragma unroll
            for (int r = 0; r < 4; ++r) {
                float hh = __builtin_amdgcn_exp2f(C2F * (acc[ni][r] + bv));
                Cf[(size_t)(rbase + r) * 512 + col] = clamp_pos(hh);
            }
        } else if (g.mode == 3) {
            unsigned short* Cb = (unsigned short*)g.C;
            float rv = __builtin_amdgcn_rcpf(g.aux[col]);   // 1/v_col
            rv = fminf(fmaxf(rv, -1e30f), 1e30f);
            #pragma unroll
            for (int r = 0; r < 4; ++r) {
                int row = rbase + r, bb = row >> 8, ss = row & 255;
                float ww = __builtin_amdgcn_exp2f(C2F * acc[ni][r]) * rv;
                ww = fminf(fmaxf(ww, -1e20f), 1e20f);
                Cb[((size_t)(bb * 64 + (col >> 3)) * 256 + ss) * 8 + (col & 7)]
                    = f2bf(ww);
            }
        } else if (g.mode == 5) {
            unsigned short* Cb = (unsigned short*)g.C;
            #pragma unroll
            for (int r = 0; r < 4; ++r)
                Cb[(size_t)(rbase + r) * 512 + col] = f2bf(acc[ni][r]);
        } else {   // mode 4: bf16 with bias
            unsigned short* Cb = (unsigned short*)g.C;
            float bv = g.aux[col];
            #pragma unroll
            for (int r = 0; r < 4; ++r)
                Cb[(size_t)(rbase + r) * 512 + col] = f2bf(acc[ni][r] + bv);
        }
    }
}

// ---------------------------------------------------------------------------
// Fused score + masked softmax + out-projection. 512 threads (8 waves).
// Score: v*sigmoid(-2(w+u)) = 1/(1/v + H*W),  H=e^{2w} (t,d), W=e^{2u}/v (s,d).
// T-PACKED layout: LDS holds {H(t0,d),H(t1,d)} float2 and {iv,iv} float2, so
//   x_d = v_pk_fma({H0,H1}, {W,W}, {iv,iv})   -- one inst, both t's.
// Pair combine over d with ONE rcp per t:
//   s = pk_add(x_d0,x_d1); p = pk_mul(x_d0,x_d1); r = {rcp(p.x),rcp(p.y)};
//   acc(pk) += s*r         -- all pk ops serve both t's per instruction.
// W-stream: 4-deep prefetch pipeline (hides cold L3/HBM first-touch).
// Softmax: p = exp2(-C2F*A) directly (shift-invariance).
// Out-proj: a2_s {a0,a1} packed; m[j] = pk_fma({c,c}, a2, m[j]).
// XCD swizzle: chunk so each XCD keeps one b-half's streams in its L2.
// ---------------------------------------------------------------------------
__global__ __launch_bounds__(512, 4) void attn_fused(
    const float* __restrict__ Hb,             // (B,T,D) fp32  e^{2w}
    const unsigned short* __restrict__ Wb,    // (B,D/8,S,8) bf16  e^{2u}/v
    const unsigned short* __restrict__ CWb,   // (B,S,D) bf16
    const unsigned short* __restrict__ OBb,   // (B,T,D) bf16
    const int*   __restrict__ mask,           // (B,S)
    const float* __restrict__ v,              // (D)
    float* __restrict__ attn_out,             // (B,T,S) fp32
    float* __restrict__ out)                  // (B,T,D) fp32
{
    // bijective XCD chunk swizzle (512 % 8 == 0)
    const int bid = blockIdx.x;
    const int bg  = (bid & 7) * (B_ * T_ / TB / 8) + (bid >> 3);
    const int b   = bg / (T_ / TB);
    const int t0  = (bg % (T_ / TB)) * TB;
    const int tid = threadIdx.x;
    const int s   = tid & 255;
    const int h   = tid >> 8;    // 0..1  (d-half in score)

    __shared__ float2 w2_s[D_];          // 4 KB  {H(t0,d), H(t1,d)}
    __shared__ float2 iv2_s[D_];         // 4 KB  {iv_d, iv_d}
    __shared__ float2 part[2][256];      // 4 KB
    __shared__ float2 wred[4];
    __shared__ float2 a2_s[256];         // 2 KB  {a(t0,s), a(t1,s)}
    __shared__ float  mixp[4][TB][D_];   // 16 KB

    {
        float h0 = Hb[(size_t)(b * T_ + t0 + 0) * D_ + tid];
        float h1 = Hb[(size_t)(b * T_ + t0 + 1) * D_ + tid];
        w2_s[tid] = make_float2(h0, h1);
        float iv = __builtin_amdgcn_rcpf(v[tid]);
        iv = fminf(fmaxf(iv, -1e30f), 1e30f);
        iv2_s[tid] = make_float2(iv, iv);
    }
    __syncthreads();

    floatx2 acc = {0.f, 0.f};
    const uint4* wb4 = (const uint4*)(Wb + ((size_t)(b * 64 + h * 32) * 256 + s) * 8);

    // 4-deep prefetch pipeline over the 32 W-chunks
    uint4 buf0 = wb4[0 * 256];
    uint4 buf1 = wb4[1 * 256];
    uint4 buf2 = wb4[2 * 256];
    uint4 buf3 = wb4[3 * 256];

    #pragma unroll
    for (int dd0 = 0; dd0 < 32; dd0 += 4) {
        uint4 c0 = buf0, c1 = buf1, c2 = buf2, c3 = buf3;
        if (dd0 + 4 < 32) {
            buf0 = wb4[(size_t)(dd0 + 4) * 256];
            buf1 = wb4[(size_t)(dd0 + 5) * 256];
            buf2 = wb4[(size_t)(dd0 + 6) * 256];
            buf3 = wb4[(size_t)(dd0 + 7) * 256];
        }
        #pragma unroll
        for (int i = 0; i < 4; ++i) {
            const uint4 ww = (i == 0) ? c0 : (i == 1) ? c1 : (i == 2) ? c2 : c3;
            const int dd = dd0 + i;
            float Ws[8];
            Ws[0] = asf(ww.x << 16); Ws[1] = asf(ww.x & 0xffff0000u);
            Ws[2] = asf(ww.y << 16); Ws[3] = asf(ww.y & 0xffff0000u);
            Ws[4] = asf(ww.z << 16); Ws[5] = asf(ww.z & 0xffff0000u);
            Ws[6] = asf(ww.w << 16); Ws[7] = asf(ww.w & 0xffff0000u);

            const int dbase = (h * 32 + dd) * 8;
            const floatx2* w2 = (const floatx2*)&w2_s[dbase];
            const floatx2* i2 = (const floatx2*)&iv2_s[dbase];

            floatx2 xd[8];
            #pragma unroll
            for (int j = 0; j < 8; ++j) {
                floatx2 wj = {Ws[j], Ws[j]};
                xd[j] = __builtin_elementwise_fma(w2[j], wj, i2[j]);
            }
            #pragma unroll
            for (int p = 0; p < 4; ++p) {
                floatx2 sm = xd[2 * p] + xd[2 * p + 1];
                floatx2 pr = xd[2 * p] * xd[2 * p + 1];
                floatx2 r = {__builtin_amdgcn_rcpf(pr.x),
                             __builtin_amdgcn_rcpf(pr.y)};
                acc = __builtin_elementwise_fma(sm, r, acc);
            }
        }
    }
    part[h][s] = make_float2(acc.x, acc.y);
    __syncthreads();

    float p0 = 0.f, p1 = 0.f;
    if (tid < 256) {
        float A0 = part[0][tid].x + part[1][tid].x;
        float A1 = part[0][tid].y + part[1][tid].y;
        float keep = 1.0f - (float)mask[b * S_ + tid];
        p0 = __builtin_amdgcn_exp2f(-C2F * A0) * keep;
        p1 = __builtin_amdgcn_exp2f(-C2F * A1) * keep;
        float s0 = p0, s1 = p1;
        #pragma unroll
        for (int off = 1; off < 64; off <<= 1) {
            s0 += __shfl_xor(s0, off);
            s1 += __shfl_xor(s1, off);
        }
        if ((tid & 63) == 0) wred[tid >> 6] = make_float2(s0, s1);
    }
    __syncthreads();

    if (tid < 256) {
        float den0 = wred[0].x + wred[1].x + wred[2].x + wred[3].x;
        float den1 = wred[0].y + wred[1].y + wred[2].y + wred[3].y;
        float a0 = p0 * __builtin_amdgcn_rcpf(den0);
        float a1 = p1 * __builtin_amdgcn_rcpf(den1);
        attn_out[(size_t)(b * T_ + t0 + 0) * S_ + tid] = a0;
        attn_out[(size_t)(b * T_ + t0 + 1) * S_ + tid] = a1;
        a2_s[tid] = make_float2(a0, a1);
    }
    __syncthreads();

    // out-projection: thread (dq=tid&127 -> d=4dq..4dq+3), s-quarter sq=tid>>7
    const int dq = tid & 127, sq = tid >> 7;
    const int sh = sq * 64;
    const unsigned short* cw = CWb + ((size_t)(b * S_) + sh) * D_ + 4 * dq;
    floatx2 m[4] = {{0.f, 0.f}, {0.f, 0.f}, {0.f, 0.f}, {0.f, 0.f}};
    #pragma unroll 8
    for (int s2 = 0; s2 < 64; ++s2) {
        uint2 cc = *(const uint2*)(cw + (size_t)s2 * D_);   // 8B coalesced
        float c0 = asf(cc.x << 16), c1 = asf(cc.x & 0xffff0000u);
        float c2 = asf(cc.y << 16), c3 = asf(cc.y & 0xffff0000u);
        float2 aa = a2_s[sh + s2];                          // b64 broadcast
        floatx2 ap = {aa.x, aa.y};
        m[0] = __builtin_elementwise_fma((floatx2){c0, c0}, ap, m[0]);
        m[1] = __builtin_elementwise_fma((floatx2){c1, c1}, ap, m[1]);
        m[2] = __builtin_elementwise_fma((floatx2){c2, c2}, ap, m[2]);
        m[3] = __builtin_elementwise_fma((floatx2){c3, c3}, ap, m[3]);
    }
    *(float4*)&mixp[sq][0][4 * dq] = make_float4(m[0].x, m[1].x, m[2].x, m[3].x);
    *(float4*)&mixp[sq][1][4 * dq] = make_float4(m[0].y, m[1].y, m[2].y, m[3].y);
    __syncthreads();

    {   // 512 threads cover TB*512 outputs (2 per thread)
        #pragma unroll
        for (int t = 0; t < TB; ++t) {
            const int d = tid;
            size_t idx = (size_t)(b * T_ + t0 + t) * D_ + d;
            float ob = asf((unsigned)OBb[idx] << 16);
            out[idx] = mixp[0][t][d] + mixp[1][t][d] + mixp[2][t][d] + mixp[3][t][d]
                     + ob;
        }
    }
}

extern "C" void kernel_launch(void* const* d_in, const int* in_sizes, int n_in,
                              void* d_out, int out_size, void* d_ws, size_t ws_size,
                              hipStream_t stream) {
    const float* output  = (const float*)d_in[0];
    const float* context = (const float*)d_in[1];
    const int*   mask    = (const int*)d_in[2];
    const float* Wq      = (const float*)d_in[3];
    const float* bq      = (const float*)d_in[4];
    const float* Wc      = (const float*)d_in[5];
    const float* v       = (const float*)d_in[6];
    const float* Wout    = (const float*)d_in[7];
    const float* bout    = (const float*)d_in[8];

    float* out  = (float*)d_out;                       // (B,T,D)
    float* attn = out + (size_t)B_ * T_ * D_;          // (B,T,S)

    char* ws = (char*)d_ws;
    float* Hb             = (float*)ws;                             // 2 MB
    unsigned short* OBb   = (unsigned short*)(ws + (2u << 20));     // 1 MB
    unsigned short* Wb    = (unsigned short*)(ws + (4u << 20));     // 1 MB
    unsigned short* out_f = (unsigned short*)(ws + (6u << 20));     // 1 MB
    unsigned short* ctx_f = (unsigned short*)(ws + (7u << 20));     // 1 MB
    unsigned short* Wq_f  = (unsigned short*)(ws + (8u << 20));     // 0.5 MB
    unsigned short* Wc_f  = (unsigned short*)(ws + (8u << 20) + (512u << 10));
    unsigned short* WoT_f = (unsigned short*)(ws + (9u << 20));     // 0.5 MB
    unsigned short* WoB_f = (unsigned short*)(ws + (9u << 20) + (512u << 10));
    unsigned short* CWb   = (unsigned short*)(ws + (10u << 20));    // 1 MB

    dim3 blk(256);

    prep<<<dim3(16, 16, 6), blk, 0, stream>>>(
        output, context, Wq, Wc, Wout, out_f, ctx_f, Wq_f, Wc_f, WoT_f, WoB_f);

    // four independent GEMMs, one dispatch (z-slices), K=512 each:
    //   z0: Hb  = clamp(exp2(C2*(output@Wq + bq)))        [mode 1]
    //   z1: Wb  = bf16 clamp(exp2(C2*(context@Wc))/v)     [mode 3]
    //   z2: OBb = bf16 (output@Wout_bot + bout)           [mode 4]
    //   z3: CWb = bf16 context@Wout_top                   [mode 5]
    GArgs gwq = { out_f, Wq_f,  bq,   Hb,  1 };
    GArgs guh = { ctx_f, Wc_f,  v,    Wb,  3 };
    GArgs gob = { out_f, WoB_f, bout, OBb, 4 };
    GArgs gcw = { ctx_f, WoT_f, NULL, CWb, 5 };
    gemm2<<<dim3(16, 16, 4), blk, 0, stream>>>(gwq, guh, gob, gcw);

    attn_fused<<<dim3(B_ * T_ / TB), dim3(512), 0, stream>>>(
        Hb, Wb, CWb, OBb, mask, v, attn, out);
}

// Round 9
// 106.927 us; speedup vs baseline: 4.2552x; 1.0070x over previous
//
#include <hip/hip_runtime.h>
#include <hip/hip_bf16.h>

#define B_ 4
#define T_ 256
#define S_ 256
#define D_ 512
#define TB 2   // t's per attention block

typedef __bf16 bf16x8 __attribute__((ext_vector_type(8)));
typedef float  floatx4 __attribute__((ext_vector_type(4)));
typedef float  floatx2 __attribute__((ext_vector_type(2)));

#define C2F 2.885390081777926f  // 2*log2(e)

static __device__ __forceinline__ unsigned short f2bf(float x) {
    __hip_bfloat16 h = __float2bfloat16(x);
    return *reinterpret_cast<unsigned short*>(&h);
}
static __device__ __forceinline__ float asf(unsigned int u) {
    float f; __builtin_memcpy(&f, &u, 4); return f;
}
static __device__ __forceinline__ float clamp_pos(float x) {
    return fminf(fmaxf(x, 1e-15f), 1e15f);
}

// ---------------------------------------------------------------------------
// Fragment-order layout (K=512 => 16 k-blocks of 32):
//   tile(mblk,kblk) = mblk*16 + kblk;  lane = (m&15) | (((k>>3)&3)<<4)
//   addr = (tile*64 + lane)*8 + (k&7)
// ---------------------------------------------------------------------------

__global__ __launch_bounds__(256) void prep(
    const float* __restrict__ output, const float* __restrict__ context,
    const float* __restrict__ Wq, const float* __restrict__ Wc,
    const float* __restrict__ Wout,
    unsigned short* __restrict__ out_f, unsigned short* __restrict__ ctx_f,
    unsigned short* __restrict__ Wq_f, unsigned short* __restrict__ Wc_f,
    unsigned short* __restrict__ WoT_f, unsigned short* __restrict__ WoB_f)
{
    const int tid = threadIdx.x;
    const int z = blockIdx.z;

    if (z >= 4) {
        const float* src = (z == 4) ? output : context;
        unsigned short* dst = (z == 4) ? out_f : ctx_f;
        const int bid  = blockIdx.y * 16 + blockIdx.x;   // 0..255
        const int tile = bid * 4 + (tid >> 6);           // 0..1023
        const int lane = tid & 63;
        const int mblk = tile >> 4, kblk = tile & 15;
        const float* s = src + (size_t)(mblk * 16 + (lane & 15)) * 512
                             + kblk * 32 + (lane >> 4) * 8;
        float4 a = *(const float4*)s;
        float4 b = *(const float4*)(s + 4);
        uint4 pk;
        pk.x = (unsigned)f2bf(a.x) | ((unsigned)f2bf(a.y) << 16);
        pk.y = (unsigned)f2bf(a.z) | ((unsigned)f2bf(a.w) << 16);
        pk.z = (unsigned)f2bf(b.x) | ((unsigned)f2bf(b.y) << 16);
        pk.w = (unsigned)f2bf(b.z) | ((unsigned)f2bf(b.w) << 16);
        *(uint4*)(dst + (size_t)tile * 512 + lane * 8) = pk;
        return;
    }

    const float* W; unsigned short* WF; int krow0;
    if      (z == 0) { W = Wq;   WF = Wq_f;  krow0 = 0;   }
    else if (z == 1) { W = Wc;   WF = Wc_f;  krow0 = 0;   }
    else if (z == 2) { W = Wout; WF = WoT_f; krow0 = 0;   }
    else             { W = Wout; WF = WoB_f; krow0 = 512; }

    const int n0 = blockIdx.x * 32;
    const int k0 = blockIdx.y * 32;

    __shared__ float tile[32][33];
    const int c = tid & 31, r = tid >> 5;
    #pragma unroll
    for (int i = 0; i < 4; ++i)
        tile[r + 8 * i][c] = W[(size_t)(krow0 + k0 + r + 8 * i) * 512 + n0 + c];
    __syncthreads();
    #pragma unroll
    for (int i = 0; i < 4; ++i) {
        const int n = n0 + r + 8 * i;
        const int k = k0 + c;
        const int tl = (n >> 4) * 16 + (k >> 5);
        const int ln = (n & 15) | (((k >> 3) & 3) << 4);
        WF[((size_t)tl * 64 + ln) * 8 + (k & 7)] = f2bf(tile[c][r + 8 * i]);
    }
}

// ---------------------------------------------------------------------------
// MFMA bf16 GEMM from fragment-order inputs. Wave tile 16m x 32n.
// Epilogue modes:
//   1: H = clamp(exp2(C2F*(acc+bq[col])), 1e-15, 1e15)  fp32 (B,T,D)
//   3: W = clamp(exp2(+C2F*acc) * rcp(v[col]), +-1e20)  bf16 [b][d>>3][s][8]
//   4: bf16 acc + bout[col]                 (OBb = output@Wout_bot + bout)
//   5: bf16 acc, natural [row][col]         (CWb = context@Wout_top)
// ---------------------------------------------------------------------------
struct GArgs {
    const unsigned short* Af;
    const unsigned short* Bf;
    const float* aux;    // bias (modes 1,4) or v (mode 3)
    void* C;
    int mode;
};

__global__ __launch_bounds__(256) void gemm2(GArgs g0, GArgs g1, GArgs g2, GArgs g3)
{
    const int z = blockIdx.z;
    GArgs g = (z == 0) ? g0 : (z == 1) ? g1 : (z == 2) ? g2 : g3;

    const int tid  = threadIdx.x;
    const int wave = tid >> 6, lane = tid & 63;
    const int l15  = lane & 15, quad = lane >> 4;
    const int mblk = blockIdx.y * 4 + wave;      // 0..63
    const int nb0  = blockIdx.x * 2;             // 0..30

    const unsigned short* Ap  = g.Af + ((size_t)mblk * 16 * 64 + lane) * 8;
    const unsigned short* Bp0 = g.Bf + ((size_t)nb0 * 16 * 64 + lane) * 8;
    const unsigned short* Bp1 = Bp0 + (size_t)16 * 64 * 8;

    floatx4 acc[2];
    acc[0] = (floatx4){0.f, 0.f, 0.f, 0.f};
    acc[1] = (floatx4){0.f, 0.f, 0.f, 0.f};

    #pragma unroll 4
    for (int k = 0; k < 16; ++k) {
        bf16x8 a  = *(const bf16x8*)(Ap  + k * 512);
        bf16x8 b0 = *(const bf16x8*)(Bp0 + k * 512);
        bf16x8 b1 = *(const bf16x8*)(Bp1 + k * 512);
        acc[0] = __builtin_amdgcn_mfma_f32_16x16x32_bf16(a, b0, acc[0], 0, 0, 0);
        acc[1] = __builtin_amdgcn_mfma_f32_16x16x32_bf16(a, b1, acc[1], 0, 0, 0);
    }

    #pragma unroll
    for (int ni = 0; ni < 2; ++ni) {
        const int col = (nb0 + ni) * 16 + l15;
        const int rbase = mblk * 16 + quad * 4;
        if (g.mode == 1) {
            float* Cf = (float*)g.C;
            float bv = g.aux[col];
            #pragma unroll
            for (int r = 0; r < 4; ++r) {
                float hh = __builtin_amdgcn_exp2f(C2F * (acc[ni][r] + bv));
                Cf[(size_t)(rbase + r) * 512 + col] = clamp_pos(hh);
            }
        } else if (g.mode == 3) {
            unsigned short* Cb = (unsigned short*)g.C;
            float rv = __builtin_amdgcn_rcpf(g.aux[col]);   // 1/v_col
            rv = fminf(fmaxf(rv, -1e30f), 1e30f);
            #pragma unroll
            for (int r = 0; r < 4; ++r) {
                int row = rbase + r, bb = row >> 8, ss = row & 255;
                float ww = __builtin_amdgcn_exp2f(C2F * acc[ni][r]) * rv;
                ww = fminf(fmaxf(ww, -1e20f), 1e20f);
                Cb[((size_t)(bb * 64 + (col >> 3)) * 256 + ss) * 8 + (col & 7)]
                    = f2bf(ww);
            }
        } else if (g.mode == 5) {
            unsigned short* Cb = (unsigned short*)g.C;
            #pragma unroll
            for (int r = 0; r < 4; ++r)
                Cb[(size_t)(rbase + r) * 512 + col] = f2bf(acc[ni][r]);
        } else {   // mode 4: bf16 with bias
            unsigned short* Cb = (unsigned short*)g.C;
            float bv = g.aux[col];
            #pragma unroll
            for (int r = 0; r < 4; ++r)
                Cb[(size_t)(rbase + r) * 512 + col] = f2bf(acc[ni][r] + bv);
        }
    }
}

// ---------------------------------------------------------------------------
// Fused score + masked softmax + out-projection. 512 threads (8 waves),
// 512 blocks = exactly 2 blocks/CU (grid-capped; higher residency caps are
// pointless -- round-4 lesson).
// Score: v*sigmoid(-2(w+u)) = 1/(1/v + H*W),  H=e^{2w} (t,d), W=e^{2u}/v (s,d).
// T-PACKED: LDS holds {H(t0,d),H(t1,d)} and {iv,iv}; one pk_fma serves both
// t's; pair combine over d with one scalar rcp per t.
// W-stream: 4-deep prefetch pipeline (hides cold L3/HBM first-touch).
// CW-stream: first 8 out-proj loads ISSUED BEFORE the softmax barriers
// (T14 issue-early/consume-late) so the cold first touches overlap softmax.
// Softmax: p = exp2(-C2F*A) directly (shift-invariance).
// XCD swizzle: chunk so each XCD keeps one b-half's streams in its L2.
// ---------------------------------------------------------------------------
__global__ __launch_bounds__(512, 4) void attn_fused(
    const float* __restrict__ Hb,             // (B,T,D) fp32  e^{2w}
    const unsigned short* __restrict__ Wb,    // (B,D/8,S,8) bf16  e^{2u}/v
    const unsigned short* __restrict__ CWb,   // (B,S,D) bf16
    const unsigned short* __restrict__ OBb,   // (B,T,D) bf16
    const int*   __restrict__ mask,           // (B,S)
    const float* __restrict__ v,              // (D)
    float* __restrict__ attn_out,             // (B,T,S) fp32
    float* __restrict__ out)                  // (B,T,D) fp32
{
    // bijective XCD chunk swizzle (512 % 8 == 0)
    const int bid = blockIdx.x;
    const int bg  = (bid & 7) * (B_ * T_ / TB / 8) + (bid >> 3);
    const int b   = bg / (T_ / TB);
    const int t0  = (bg % (T_ / TB)) * TB;
    const int tid = threadIdx.x;
    const int s   = tid & 255;
    const int h   = tid >> 8;    // 0..1  (d-half in score)

    __shared__ float2 w2_s[D_];          // 4 KB  {H(t0,d), H(t1,d)}
    __shared__ float2 iv2_s[D_];         // 4 KB  {iv_d, iv_d}
    __shared__ float2 part[2][256];      // 4 KB
    __shared__ float2 wred[4];
    __shared__ float2 a2_s[256];         // 2 KB  {a(t0,s), a(t1,s)}
    __shared__ float  mixp[4][TB][D_];   // 16 KB

    {
        float h0 = Hb[(size_t)(b * T_ + t0 + 0) * D_ + tid];
        float h1 = Hb[(size_t)(b * T_ + t0 + 1) * D_ + tid];
        w2_s[tid] = make_float2(h0, h1);
        float iv = __builtin_amdgcn_rcpf(v[tid]);
        iv = fminf(fmaxf(iv, -1e30f), 1e30f);
        iv2_s[tid] = make_float2(iv, iv);
    }
    __syncthreads();

    floatx2 acc = {0.f, 0.f};
    const uint4* wb4 = (const uint4*)(Wb + ((size_t)(b * 64 + h * 32) * 256 + s) * 8);

    // 4-deep prefetch pipeline over the 32 W-chunks
    uint4 buf0 = wb4[0 * 256];
    uint4 buf1 = wb4[1 * 256];
    uint4 buf2 = wb4[2 * 256];
    uint4 buf3 = wb4[3 * 256];

    #pragma unroll
    for (int dd0 = 0; dd0 < 32; dd0 += 4) {
        uint4 c0 = buf0, c1 = buf1, c2 = buf2, c3 = buf3;
        if (dd0 + 4 < 32) {
            buf0 = wb4[(size_t)(dd0 + 4) * 256];
            buf1 = wb4[(size_t)(dd0 + 5) * 256];
            buf2 = wb4[(size_t)(dd0 + 6) * 256];
            buf3 = wb4[(size_t)(dd0 + 7) * 256];
        }
        #pragma unroll
        for (int i = 0; i < 4; ++i) {
            const uint4 ww = (i == 0) ? c0 : (i == 1) ? c1 : (i == 2) ? c2 : c3;
            const int dd = dd0 + i;
            float Ws[8];
            Ws[0] = asf(ww.x << 16); Ws[1] = asf(ww.x & 0xffff0000u);
            Ws[2] = asf(ww.y << 16); Ws[3] = asf(ww.y & 0xffff0000u);
            Ws[4] = asf(ww.z << 16); Ws[5] = asf(ww.z & 0xffff0000u);
            Ws[6] = asf(ww.w << 16); Ws[7] = asf(ww.w & 0xffff0000u);

            const int dbase = (h * 32 + dd) * 8;
            const floatx2* w2 = (const floatx2*)&w2_s[dbase];
            const floatx2* i2 = (const floatx2*)&iv2_s[dbase];

            floatx2 xd[8];
            #pragma unroll
            for (int j = 0; j < 8; ++j) {
                floatx2 wj = {Ws[j], Ws[j]};
                xd[j] = __builtin_elementwise_fma(w2[j], wj, i2[j]);
            }
            #pragma unroll
            for (int p = 0; p < 4; ++p) {
                floatx2 sm = xd[2 * p] + xd[2 * p + 1];
                floatx2 pr = xd[2 * p] * xd[2 * p + 1];
                floatx2 r = {__builtin_amdgcn_rcpf(pr.x),
                             __builtin_amdgcn_rcpf(pr.y)};
                acc = __builtin_elementwise_fma(sm, r, acc);
            }
        }
    }
    part[h][s] = make_float2(acc.x, acc.y);

    // --- issue-early CW prefetch: first 8 out-proj loads in flight before
    // the softmax barriers (their latency hides under softmax) -------------
    const int dq = tid & 127, sq = tid >> 7;
    const int sh = sq * 64;
    const unsigned short* cw = CWb + ((size_t)(b * S_) + sh) * D_ + 4 * dq;
    uint2 cpre[8];
    #pragma unroll
    for (int i = 0; i < 8; ++i)
        cpre[i] = *(const uint2*)(cw + (size_t)i * D_);

    __syncthreads();

    float p0 = 0.f, p1 = 0.f;
    if (tid < 256) {
        float A0 = part[0][tid].x + part[1][tid].x;
        float A1 = part[0][tid].y + part[1][tid].y;
        float keep = 1.0f - (float)mask[b * S_ + tid];
        p0 = __builtin_amdgcn_exp2f(-C2F * A0) * keep;
        p1 = __builtin_amdgcn_exp2f(-C2F * A1) * keep;
        float s0 = p0, s1 = p1;
        #pragma unroll
        for (int off = 1; off < 64; off <<= 1) {
            s0 += __shfl_xor(s0, off);
            s1 += __shfl_xor(s1, off);
        }
        if ((tid & 63) == 0) wred[tid >> 6] = make_float2(s0, s1);
    }
    __syncthreads();

    if (tid < 256) {
        float den0 = wred[0].x + wred[1].x + wred[2].x + wred[3].x;
        float den1 = wred[0].y + wred[1].y + wred[2].y + wred[3].y;
        float a0 = p0 * __builtin_amdgcn_rcpf(den0);
        float a1 = p1 * __builtin_amdgcn_rcpf(den1);
        attn_out[(size_t)(b * T_ + t0 + 0) * S_ + tid] = a0;
        attn_out[(size_t)(b * T_ + t0 + 1) * S_ + tid] = a1;
        a2_s[tid] = make_float2(a0, a1);
    }
    __syncthreads();

    // out-projection: thread (dq -> d=4dq..4dq+3), s-quarter sq
    floatx2 m[4] = {{0.f, 0.f}, {0.f, 0.f}, {0.f, 0.f}, {0.f, 0.f}};
    #pragma unroll
    for (int s2 = 0; s2 < 8; ++s2) {
        uint2 cc = cpre[s2];
        float c0 = asf(cc.x << 16), c1 = asf(cc.x & 0xffff0000u);
        float c2 = asf(cc.y << 16), c3 = asf(cc.y & 0xffff0000u);
        float2 aa = a2_s[sh + s2];
        floatx2 ap = {aa.x, aa.y};
        m[0] = __builtin_elementwise_fma((floatx2){c0, c0}, ap, m[0]);
        m[1] = __builtin_elementwise_fma((floatx2){c1, c1}, ap, m[1]);
        m[2] = __builtin_elementwise_fma((floatx2){c2, c2}, ap, m[2]);
        m[3] = __builtin_elementwise_fma((floatx2){c3, c3}, ap, m[3]);
    }
    #pragma unroll 8
    for (int s2 = 8; s2 < 64; ++s2) {
        uint2 cc = *(const uint2*)(cw + (size_t)s2 * D_);   // 8B coalesced
        float c0 = asf(cc.x << 16), c1 = asf(cc.x & 0xffff0000u);
        float c2 = asf(cc.y << 16), c3 = asf(cc.y & 0xffff0000u);
        float2 aa = a2_s[sh + s2];                          // b64 broadcast
        floatx2 ap = {aa.x, aa.y};
        m[0] = __builtin_elementwise_fma((floatx2){c0, c0}, ap, m[0]);
        m[1] = __builtin_elementwise_fma((floatx2){c1, c1}, ap, m[1]);
        m[2] = __builtin_elementwise_fma((floatx2){c2, c2}, ap, m[2]);
        m[3] = __builtin_elementwise_fma((floatx2){c3, c3}, ap, m[3]);
    }
    *(float4*)&mixp[sq][0][4 * dq] = make_float4(m[0].x, m[1].x, m[2].x, m[3].x);
    *(float4*)&mixp[sq][1][4 * dq] = make_float4(m[0].y, m[1].y, m[2].y, m[3].y);
    __syncthreads();

    {   // 512 threads cover TB*512 outputs (2 per thread)
        #pragma unroll
        for (int t = 0; t < TB; ++t) {
            const int d = tid;
            size_t idx = (size_t)(b * T_ + t0 + t) * D_ + d;
            float ob = asf((unsigned)OBb[idx] << 16);
            out[idx] = mixp[0][t][d] + mixp[1][t][d] + mixp[2][t][d] + mixp[3][t][d]
                     + ob;
        }
    }
}

extern "C" void kernel_launch(void* const* d_in, const int* in_sizes, int n_in,
                              void* d_out, int out_size, void* d_ws, size_t ws_size,
                              hipStream_t stream) {
    const float* output  = (const float*)d_in[0];
    const float* context = (const float*)d_in[1];
    const int*   mask    = (const int*)d_in[2];
    const float* Wq      = (const float*)d_in[3];
    const float* bq      = (const float*)d_in[4];
    const float* Wc      = (const float*)d_in[5];
    const float* v       = (const float*)d_in[6];
    const float* Wout    = (const float*)d_in[7];
    const float* bout    = (const float*)d_in[8];

    float* out  = (float*)d_out;                       // (B,T,D)
    float* attn = out + (size_t)B_ * T_ * D_;          // (B,T,S)

    char* ws = (char*)d_ws;
    float* Hb             = (float*)ws;                             // 2 MB
    unsigned short* OBb   = (unsigned short*)(ws + (2u << 20));     // 1 MB
    unsigned short* Wb    = (unsigned short*)(ws + (4u << 20));     // 1 MB
    unsigned short* out_f = (unsigned short*)(ws + (6u << 20));     // 1 MB
    unsigned short* ctx_f = (unsigned short*)(ws + (7u << 20));     // 1 MB
    unsigned short* Wq_f  = (unsigned short*)(ws + (8u << 20));     // 0.5 MB
    unsigned short* Wc_f  = (unsigned short*)(ws + (8u << 20) + (512u << 10));
    unsigned short* WoT_f = (unsigned short*)(ws + (9u << 20));     // 0.5 MB
    unsigned short* WoB_f = (unsigned short*)(ws + (9u << 20) + (512u << 10));
    unsigned short* CWb   = (unsigned short*)(ws + (10u << 20));    // 1 MB

    dim3 blk(256);

    prep<<<dim3(16, 16, 6), blk, 0, stream>>>(
        output, context, Wq, Wc, Wout, out_f, ctx_f, Wq_f, Wc_f, WoT_f, WoB_f);

    // four independent GEMMs, one dispatch (z-slices), K=512 each:
    //   z0: Hb  = clamp(exp2(C2*(output@Wq + bq)))        [mode 1]
    //   z1: Wb  = bf16 clamp(exp2(C2*(context@Wc))/v)     [mode 3]
    //   z2: OBb = bf16 (output@Wout_bot + bout)           [mode 4]
    //   z3: CWb = bf16 context@Wout_top                   [mode 5]
    GArgs gwq = { out_f, Wq_f,  bq,   Hb,  1 };
    GArgs guh = { ctx_f, Wc_f,  v,    Wb,  3 };
    GArgs gob = { out_f, WoB_f, bout, OBb, 4 };
    GArgs gcw = { ctx_f, WoT_f, NULL, CWb, 5 };
    gemm2<<<dim3(16, 16, 4), blk, 0, stream>>>(gwq, guh, gob, gcw);

    attn_fused<<<dim3(B_ * T_ / TB), dim3(512), 0, stream>>>(
        Hb, Wb, CWb, OBb, mask, v, attn, out);
}